// Round 14
// baseline (470.701 us; speedup 1.0000x reference)
//
#include <hip/hip_runtime.h>
#include <hip/hip_bf16.h>
#include <hip/hip_fp16.h>
#include <cstddef>
#include <cstdint>

#define NNODES 50000
#define NEDGES 1600000
#define DIM 256
#define HID 128
#define FCU 1024
#define NCLS 16

// CSR-build geometry
#define NBKT 256
#define BW 196
#define NBLK_A 64
#define EPB (NEDGES / NBLK_A)
#define CAPB 8192

// degree-histogram geometry
#define DCHUNK 12800
#define DSLICE 64
#define DEPB (NEDGES / DSLICE)

typedef short s16x8 __attribute__((ext_vector_type(8)));
typedef _Float16 f16x8 __attribute__((ext_vector_type(8)));
typedef float f32x4 __attribute__((ext_vector_type(4)));
#define MFMA16 __builtin_amdgcn_mfma_f32_16x16x32_bf16
#define MFMAH  __builtin_amdgcn_mfma_f32_16x16x32_f16

typedef unsigned short u16;
typedef unsigned int u32;

__device__ inline u16 f2bf(float f) {
    u32 u = __float_as_uint(f);
    return (u16)((u + 0x7FFF + ((u >> 16) & 1)) >> 16);
}
__device__ inline float bf2f(u16 h) { return __uint_as_float(((u32)h) << 16); }
__device__ inline void split2(float v, u16& h, u16& l) {
    h = f2bf(v);
    l = f2bf(v - bf2f(h));
}

// ---------------- graph preprocessing ----------------

__global__ __launch_bounds__(256) void histDeg(const int* __restrict__ ei, int* __restrict__ degS) {
    __shared__ int h[DCHUNK];
    int chunk = blockIdx.x >> 6;
    int slice = blockIdx.x & (DSLICE - 1);
    int t = threadIdx.x;
    int base0 = chunk * DCHUNK;
    for (int i = t; i < DCHUNK; i += 256) h[i] = 0;
    __syncthreads();
    int base = slice * DEPB;
    for (int e = base + t; e < base + DEPB; e += 256) {
        int s = ei[e] - base0;
        if ((unsigned)s < (unsigned)DCHUNK) atomicAdd(&h[s], 1);
    }
    __syncthreads();
    int lim = NNODES - base0; if (lim > DCHUNK) lim = DCHUNK;
    for (int i = t; i < lim; i += 256) {
        int v = h[i];
        if (v) atomicAdd(&degS[base0 + i], v);
    }
}

__global__ void norm_kernel(const int* __restrict__ degS, float* __restrict__ nrm) {
    int i = blockIdx.x * blockDim.x + threadIdx.x;
    if (i < NNODES) nrm[i] = rsqrtf((float)(degS[i] + 1));
}

__global__ __launch_bounds__(1024) void histA(const int* __restrict__ ei, int* __restrict__ hist) {
    __shared__ int h[NBKT];
    int blk = blockIdx.x, t = threadIdx.x;
    if (t < NBKT) h[t] = 0;
    __syncthreads();
    int base = blk * EPB;
    for (int e = base + t; e < base + EPB; e += 1024) {
        int dst = ei[NEDGES + e];
        atomicAdd(&h[dst / BW], 1);
    }
    __syncthreads();
    if (t < NBKT) hist[t * NBLK_A + blk] = h[t];
}

__global__ __launch_bounds__(1024) void scanh_a(int* __restrict__ hist, int* __restrict__ bsum) {
    __shared__ int s[1024];
    int b = blockIdx.x, t = threadIdx.x, i = b * 1024 + t;
    int v = hist[i];
    s[t] = v;
    __syncthreads();
    for (int off = 1; off < 1024; off <<= 1) {
        int x = (t >= off) ? s[t - off] : 0;
        __syncthreads();
        s[t] += x;
        __syncthreads();
    }
    hist[i] = s[t] - v;
    if (t == 1023) bsum[b] = s[1023];
}
__global__ void scanh_b(int* __restrict__ bsum) {
    if (threadIdx.x == 0 && blockIdx.x == 0) {
        int a = 0;
        for (int j = 0; j < 16; ++j) { int t = bsum[j]; bsum[j] = a; a += t; }
    }
}
__global__ __launch_bounds__(1024) void scanh_c(int* __restrict__ hist, const int* __restrict__ bsum) {
    int i = blockIdx.x * 1024 + threadIdx.x;
    hist[i] += bsum[blockIdx.x];
}

__global__ __launch_bounds__(1024) void bucket_fill(const int* __restrict__ ei,
                                                    const int* __restrict__ hist,
                                                    u32* __restrict__ packed) {
    __shared__ int cur[NBKT];
    int blk = blockIdx.x, t = threadIdx.x;
    if (t < NBKT) cur[t] = hist[t * NBLK_A + blk];
    __syncthreads();
    int base = blk * EPB;
    for (int e = base + t; e < base + EPB; e += 1024) {
        int src = ei[e], dst = ei[NEDGES + e];
        int p = atomicAdd(&cur[dst / BW], 1);
        packed[p] = ((u32)dst << 16) | (u32)src;
    }
}

__global__ __launch_bounds__(256) void bucket_csr(const u32* __restrict__ packed,
                                                  const int* __restrict__ hist,
                                                  int* __restrict__ rowptr, u16* __restrict__ csr) {
    __shared__ u32 st[CAPB];
    __shared__ u16 so[CAPB];
    __shared__ int cnt[256], excl[256];
    int b = blockIdx.x, t = threadIdx.x;
    int ebase = hist[b * NBLK_A];
    int eend  = (b < NBKT - 1) ? hist[(b + 1) * NBLK_A] : NEDGES;
    int nE = eend - ebase;
    if (nE > CAPB) nE = CAPB;
    cnt[t] = 0;
    __syncthreads();
    for (int i = t; i < nE; i += 256) {
        u32 p = packed[ebase + i];
        st[i] = p;
        atomicAdd(&cnt[(int)(p >> 16) - b * BW], 1);
    }
    __syncthreads();
    int v = cnt[t];
    excl[t] = v;
    __syncthreads();
    for (int off = 1; off < 256; off <<= 1) {
        int x = (t >= off) ? excl[t - off] : 0;
        __syncthreads();
        excl[t] += x;
        __syncthreads();
    }
    int ex = excl[t] - v;
    int node = b * BW + t;
    if (t < BW && node < NNODES) rowptr[node] = ebase + ex;
    if (b == NBKT - 1 && t == 0) rowptr[NNODES] = NEDGES;
    cnt[t] = ex;
    __syncthreads();
    for (int i = t; i < nE; i += 256) {
        u32 p = st[i];
        int pos = atomicAdd(&cnt[(int)(p >> 16) - b * BW], 1);
        so[pos] = (u16)(p & 0xFFFF);
    }
    __syncthreads();
    for (int i = t; i < nE; i += 256) csr[ebase + i] = so[i];
}

// ---------------- conversions ----------------

__global__ __launch_bounds__(256) void conv_x(const float* __restrict__ x,
                                              u16* __restrict__ xh, u16* __restrict__ xl) {
    int i = blockIdx.x * blockDim.x + threadIdx.x;
    const float4 v = *reinterpret_cast<const float4*>(x + (size_t)i * 4);
    u16 h0, l0, h1, l1, h2, l2, h3, l3;
    split2(v.x, h0, l0); split2(v.y, h1, l1); split2(v.z, h2, l2); split2(v.w, h3, l3);
    ushort4 hv = make_ushort4(h0, h1, h2, h3), lv = make_ushort4(l0, l1, l2, l3);
    *reinterpret_cast<ushort4*>(xh + (size_t)i * 4) = hv;
    *reinterpret_cast<ushort4*>(xl + (size_t)i * 4) = lv;
}

// gcn0W only: hi/lo transposed planes (split-3 consumer)
__global__ __launch_bounds__(256) void conv_wT(const float* __restrict__ W, int K, int N,
                                               u16* __restrict__ outH, u16* __restrict__ outL) {
    int o = blockIdx.x * blockDim.x + threadIdx.x;
    if (o < K * N) {
        int n = o / K, k = o - n * K;
        u16 h, l;
        split2(W[(size_t)k * N + n], h, l);
        outH[o] = h; outL[o] = l;
    }
}

// all single-plane weight conversions fused
__global__ __launch_bounds__(256) void conv_weights(
    const float* __restrict__ fc0W, u16* __restrict__ F0Th,
    const float* __restrict__ w1,    u16* __restrict__ w1Th,
    const float* __restrict__ gcn1W, u16* __restrict__ W1Th,
    const float* __restrict__ gcn2W, u16* __restrict__ W2Th,
    const float* __restrict__ fc1W,  __half* __restrict__ W1f)
{
    int b = blockIdx.x, t = threadIdx.x;
    if (b < 512) {
        int o = b * 256 + t;
        int n = o >> 7, k = o & 127;
        F0Th[o] = f2bf(fc0W[(size_t)k * FCU + n]);
    } else if (b < 576) {
        int o = (b - 512) * 256 + t;
        int n = o >> 7, k = o & 127;
        w1Th[o] = f2bf(w1[(size_t)k * HID + n]);
    } else if (b < 640) {
        int o = (b - 576) * 256 + t;
        int n = o >> 7, k = o & 127;
        W1Th[o] = f2bf(gcn1W[(size_t)k * HID + n]);
    } else if (b < 704) {
        int o = (b - 640) * 256 + t;
        int n = o >> 7, k = o & 127;
        W2Th[o] = f2bf(gcn2W[(size_t)k * HID + n]);
    } else {
        int o = (b - 704) * 256 + t;
        int n = o >> 10, k = o & 1023;
        W1f[o] = __float2half(fc1W[(size_t)k * NCLS + n]);
    }
}

// ---------------- aggregation (round-9 proven; VAR 0 relu / VAR 1 plain) ----------------

template<int VAR, int WLO>
__global__ __launch_bounds__(256) void agg_fast(
    const __half* __restrict__ g, const float* __restrict__ nrm,
    const int* __restrict__ rowptr, const u16* __restrict__ csr,
    const float* __restrict__ bias,
    u16* __restrict__ outH, u16* __restrict__ outL)
{
    int w = threadIdx.x >> 6, lane = threadIdx.x & 63;
    int i = blockIdx.x * 4 + w;
    if (i >= NNODES) return;
    const __half2* gp = reinterpret_cast<const __half2*>(g);
    size_t lrow = (size_t)i * 64 + lane;
    float2 acc = __half22float2(gp[lrow]);
    int e0 = rowptr[i], e1 = rowptr[i + 1];
    int e = e0;
    for (; e + 8 <= e1; e += 8) {
        int s[8];
#pragma unroll
        for (int q = 0; q < 8; ++q) s[q] = csr[e + q];
        __half2 v[8];
#pragma unroll
        for (int q = 0; q < 8; ++q) v[q] = gp[(size_t)s[q] * 64 + lane];
#pragma unroll
        for (int q = 0; q < 8; ++q) {
            float2 f = __half22float2(v[q]);
            acc.x += f.x; acc.y += f.y;
        }
    }
    for (; e < e1; ++e) {
        int s = csr[e];
        float2 f = __half22float2(gp[(size_t)s * 64 + lane]);
        acc.x += f.x; acc.y += f.y;
    }
    float ni = nrm[i];
    const float2 b = *reinterpret_cast<const float2*>(bias + lane * 2);
    float v0 = fmaf(ni, acc.x, b.x);
    float v1 = fmaf(ni, acc.y, b.y);
    if (VAR != 1) { v0 = fmaxf(v0, 0.f); v1 = fmaxf(v1, 0.f); }
    if (WLO) {
        u16 h0, l0, h1v, l1v;
        split2(v0, h0, l0);
        split2(v1, h1v, l1v);
        *reinterpret_cast<ushort2*>(outH + (size_t)i * HID + lane * 2) = make_ushort2(h0, h1v);
        *reinterpret_cast<ushort2*>(outL + (size_t)i * HID + lane * 2) = make_ushort2(l0, l1v);
    } else {
        *reinterpret_cast<ushort2*>(outH + (size_t)i * HID + lane * 2) = make_ushort2(f2bf(v0), f2bf(v1));
    }
}

// ---------------- split/single-plane bf16 MFMA GEMM: [M,K] @ [K,128] ----------------

template<int K, int MODE, int PL>
__global__ __launch_bounds__(256) void gemm_split(
    const u16* __restrict__ Ah, const u16* __restrict__ Al,
    const u16* __restrict__ BTh, const u16* __restrict__ BTl,
    const float* __restrict__ pnb, const float* __restrict__ nrmv,
    __half* __restrict__ outG, u16* __restrict__ outH, int M)
{
    const int PK = 40;
    __shared__ __align__(16) u16 AsH[64 * PK];
    __shared__ __align__(16) u16 BsH[128 * PK];
    __shared__ __align__(16) u16 AsL[PL == 3 ? 64 * PK : 1];
    __shared__ __align__(16) u16 BsL[PL == 3 ? 128 * PK : 1];
    int tid = threadIdx.x, lane = tid & 63, w = tid >> 6;
    int wr = w >> 1, wc = w & 1;
    int l15 = lane & 15, l4 = lane >> 4;
    int blockRow = blockIdx.x * 64;
    f32x4 acc[2][4] = {};

    for (int kk = 0; kk < K; kk += 32) {
        {
            int row = tid >> 2, kc = (tid & 3) * 8;
            int gr = blockRow + row; if (gr >= M) gr = M - 1;
            *(s16x8*)&AsH[row * PK + kc] = *(const s16x8*)&Ah[(size_t)gr * K + kk + kc];
            if (PL == 3)
                *(s16x8*)&AsL[row * PK + kc] = *(const s16x8*)&Al[(size_t)gr * K + kk + kc];
        }
#pragma unroll
        for (int i2 = 0; i2 < 2; ++i2) {
            int idx = tid + i2 * 256;
            int n = idx >> 2, kc = (idx & 3) * 8;
            *(s16x8*)&BsH[n * PK + kc] = *(const s16x8*)&BTh[(size_t)n * K + kk + kc];
            if (PL == 3)
                *(s16x8*)&BsL[n * PK + kc] = *(const s16x8*)&BTl[(size_t)n * K + kk + kc];
        }
        __syncthreads();
        s16x8 ah[2], al[2], bh[4], bl[4];
#pragma unroll
        for (int mi = 0; mi < 2; ++mi) {
            ah[mi] = *(const s16x8*)&AsH[(wr * 32 + mi * 16 + l15) * PK + 8 * l4];
            if (PL == 3) al[mi] = *(const s16x8*)&AsL[(wr * 32 + mi * 16 + l15) * PK + 8 * l4];
        }
#pragma unroll
        for (int ni = 0; ni < 4; ++ni) {
            bh[ni] = *(const s16x8*)&BsH[(wc * 64 + ni * 16 + l15) * PK + 8 * l4];
            if (PL == 3) bl[ni] = *(const s16x8*)&BsL[(wc * 64 + ni * 16 + l15) * PK + 8 * l4];
        }
#pragma unroll
        for (int mi = 0; mi < 2; ++mi)
#pragma unroll
            for (int ni = 0; ni < 4; ++ni) {
                acc[mi][ni] = MFMA16(ah[mi], bh[ni], acc[mi][ni], 0, 0, 0);
                if (PL == 3) {
                    acc[mi][ni] = MFMA16(ah[mi], bl[ni], acc[mi][ni], 0, 0, 0);
                    acc[mi][ni] = MFMA16(al[mi], bh[ni], acc[mi][ni], 0, 0, 0);
                }
            }
        __syncthreads();
    }
#pragma unroll
    for (int mi = 0; mi < 2; ++mi)
#pragma unroll
        for (int ni = 0; ni < 4; ++ni) {
            int c = wc * 64 + ni * 16 + l15;
#pragma unroll
            for (int j = 0; j < 4; ++j) {
                int r = blockRow + wr * 32 + mi * 16 + l4 * 4 + j;
                if (r < M) {
                    if (MODE == 0) {
                        outG[(size_t)r * 128 + c] = __float2half(nrmv[r] * acc[mi][ni][j]);
                    } else {
                        float v = fmaxf(acc[mi][ni][j] + pnb[(size_t)r * 128 + c], 0.f);
                        outH[(size_t)r * 128 + c] = f2bf(v);
                    }
                }
            }
        }
}

// ---------------- FUSED agg2 + fc head ----------------
// Block = 32 nodes, 4 waves. Phase 1: wave w aggregates nodes w*8..w*8+7
// (relu + h1 residual), writes bf16 rows to XOR-swizzled LDS hA.
// Phase 2: r11's proven fc body (BM=32, B-prefetch), A-fragments from hA.
// h never touches global memory; fc compute overlaps other blocks' gathers.

__global__ __launch_bounds__(256) void agg_fc(
    const __half* __restrict__ g, const float* __restrict__ nrm,
    const int* __restrict__ rowptr, const u16* __restrict__ csr,
    const float* __restrict__ bias,
    const u16* __restrict__ h1H, const u16* __restrict__ h1L,
    const u16* __restrict__ BTh,
    const float* __restrict__ fc0b,
    const __half* __restrict__ W1f,
    const float* __restrict__ fc1b,
    float* __restrict__ out, int M)
{
    __shared__ __align__(16) u16 hA[32 * 128];     // h rows bf16, 8-elem XOR swizzle
    __shared__ __align__(16) u16 vs[32 * 128];
    __shared__ __align__(16) u16 W1s[16 * 128];
    int tid = threadIdx.x, lane = tid & 63, w = tid >> 6;
    int l15 = lane & 15, l4 = lane >> 4;
    int blockRow = blockIdx.x * 32;

    // fc B prefetch (independent of agg; drains during gather phase)
    s16x8 bcur[2][4];
#pragma unroll
    for (int ni = 0; ni < 2; ++ni)
#pragma unroll
        for (int ks = 0; ks < 4; ++ks)
            bcur[ni][ks] = *(const s16x8*)&BTh[(size_t)(w * 32 + ni * 16 + l15) * HID + ks * 32 + 8 * l4];

    // ---- phase 1: aggregation (8 nodes per wave) ----
    const __half2* gp = reinterpret_cast<const __half2*>(g);
    const float2 bb = *reinterpret_cast<const float2*>(bias + lane * 2);
    int colc = lane >> 2;            // 8-elem block index of col=lane*2
    int colr = (lane * 2) & 7;
#pragma unroll 1
    for (int k = 0; k < 8; ++k) {
        int row = w * 8 + k;
        int i = blockRow + row;
        float v0 = 0.f, v1 = 0.f;
        if (i < M) {
            float2 acc = __half22float2(gp[(size_t)i * 64 + lane]);
            int e0 = rowptr[i], e1 = rowptr[i + 1];
            int e = e0;
            for (; e + 8 <= e1; e += 8) {
                int s[8];
#pragma unroll
                for (int q = 0; q < 8; ++q) s[q] = csr[e + q];
                __half2 vv[8];
#pragma unroll
                for (int q = 0; q < 8; ++q) vv[q] = gp[(size_t)s[q] * 64 + lane];
#pragma unroll
                for (int q = 0; q < 8; ++q) {
                    float2 f = __half22float2(vv[q]);
                    acc.x += f.x; acc.y += f.y;
                }
            }
            for (; e < e1; ++e) {
                float2 f = __half22float2(gp[(size_t)csr[e] * 64 + lane]);
                acc.x += f.x; acc.y += f.y;
            }
            float ni_ = nrm[i];
            v0 = fmaxf(fmaf(ni_, acc.x, bb.x), 0.f);
            v1 = fmaxf(fmaf(ni_, acc.y, bb.y), 0.f);
            ushort2 rh = *reinterpret_cast<const ushort2*>(h1H + (size_t)i * HID + lane * 2);
            ushort2 rl = *reinterpret_cast<const ushort2*>(h1L + (size_t)i * HID + lane * 2);
            v0 += bf2f(rh.x) + bf2f(rl.x);
            v1 += bf2f(rh.y) + bf2f(rl.y);
        }
        int cs = colc ^ (row & 7);
        *reinterpret_cast<ushort2*>(&hA[row * 128 + (cs << 3) + colr]) =
            make_ushort2(f2bf(v0), f2bf(v1));
    }
    __syncthreads();

    // ---- phase 2: fc (r11 structure, A from hA) ----
    s16x8 ahr[2][4];
#pragma unroll
    for (int mi = 0; mi < 2; ++mi) {
        int row = mi * 16 + l15;
#pragma unroll
        for (int ks = 0; ks < 4; ++ks)
            ahr[mi][ks] = *(const s16x8*)&hA[row * 128 + (((ks * 4 + l4) ^ (row & 7)) << 3)];
    }

    f32x4 acc2 = {0.f, 0.f, 0.f, 0.f};
#pragma unroll
    for (int cc = 0; cc < FCU / 128; ++cc) {
        int co = cc * 128;
        s16x8 bnxt[2][4];
        if (cc + 1 < FCU / 128) {
#pragma unroll
            for (int ni = 0; ni < 2; ++ni)
#pragma unroll
                for (int ks = 0; ks < 4; ++ks)
                    bnxt[ni][ks] = *(const s16x8*)&BTh[(size_t)(co + 128 + w * 32 + ni * 16 + l15) * HID + ks * 32 + 8 * l4];
        }

        f32x4 acc[2][2] = {};
#pragma unroll
        for (int ks = 0; ks < 4; ++ks)
#pragma unroll
            for (int mi = 0; mi < 2; ++mi)
#pragma unroll
                for (int ni = 0; ni < 2; ++ni)
                    acc[mi][ni] = MFMA16(ahr[mi][ks], bcur[ni][ks], acc[mi][ni], 0, 0, 0);

        {
            int cls = tid >> 4, kc = (tid & 15) * 8;
            s16x8 t = *(const s16x8*)&W1f[(size_t)cls * FCU + co + kc];
            *(s16x8*)&W1s[cls * 128 + (kc ^ ((cls & 7) << 3))] = t;
        }
#pragma unroll
        for (int mi = 0; mi < 2; ++mi)
#pragma unroll
            for (int ni = 0; ni < 2; ++ni) {
                int unit = w * 32 + ni * 16 + l15;
                float b0v = fc0b[co + unit];
#pragma unroll
                for (int j = 0; j < 4; ++j) {
                    int rl = mi * 16 + l4 * 4 + j;
                    float v = fmaxf(acc[mi][ni][j] + b0v, 0.f);
                    vs[rl * 128 + (unit ^ ((rl & 7) << 3))] = __half_as_ushort(__float2half(v));
                }
            }
        __syncthreads();

        if (w < 2) {
#pragma unroll
            for (int ks = 0; ks < 4; ++ks) {
                int row = w * 16 + l15;
                int colk = ks * 32 + 8 * l4;
                f16x8 a2 = *(const f16x8*)&vs[row * 128 + (colk ^ ((row & 7) << 3))];
                f16x8 b2 = *(const f16x8*)&W1s[l15 * 128 + (colk ^ ((l15 & 7) << 3))];
                acc2 = MFMAH(a2, b2, acc2, 0, 0, 0);
            }
        }
        __syncthreads();

        if (cc + 1 < FCU / 128) {
#pragma unroll
            for (int ni = 0; ni < 2; ++ni)
#pragma unroll
                for (int ks = 0; ks < 4; ++ks)
                    bcur[ni][ks] = bnxt[ni][ks];
        }
    }

    if (w < 2) {
#pragma unroll
        for (int j = 0; j < 4; ++j) {
            int gr = blockRow + w * 16 + l4 * 4 + j;
            if (gr < M) out[(size_t)gr * NCLS + l15] = acc2[j] + fc1b[l15];
        }
    }
}

// ---------------- launch ----------------

extern "C" void kernel_launch(void* const* d_in, const int* in_sizes, int n_in,
                              void* d_out, int out_size, void* d_ws, size_t ws_size,
                              hipStream_t stream)
{
    const float* x     = (const float*)d_in[0];
    const int*   ei    = (const int*)d_in[1];
    const float* gcn0W = (const float*)d_in[2];
    const float* gcn0b = (const float*)d_in[3];
    const float* gcn1W = (const float*)d_in[4];
    const float* gcn1b = (const float*)d_in[5];
    const float* gcn2W = (const float*)d_in[6];
    const float* gcn2b = (const float*)d_in[7];
    const float* w1    = (const float*)d_in[8];
    const float* b1    = (const float*)d_in[9];
    const float* fc0W  = (const float*)d_in[10];
    const float* fc0b  = (const float*)d_in[11];
    const float* fc1W  = (const float*)d_in[12];
    const float* fc1b  = (const float*)d_in[13];
    float* out = (float*)d_out;

    char* ws = (char*)d_ws;
    size_t off = 0;
    auto alloc = [&](size_t bytes) -> void* {
        void* p = ws + off;
        off = (off + bytes + 255) & ~(size_t)255;
        return p;
    };
    int* degS   = (int*)alloc((size_t)NNODES * 4);
    int* rowptr = (int*)alloc((size_t)(NNODES + 1) * 4);
    int* hist   = (int*)alloc((size_t)NBKT * NBLK_A * 4);
    int* bsum   = (int*)alloc(64 * 4);
    u32* packed = (u32*)alloc((size_t)NEDGES * 4);
    u16* csr    = (u16*)alloc((size_t)NEDGES * 2);
    float* nrm  = (float*)alloc((size_t)NNODES * 4);
    u16* W0Th = (u16*)alloc((size_t)DIM * HID * 2);  u16* W0Tl = (u16*)alloc((size_t)DIM * HID * 2);
    u16* w1Th = (u16*)alloc((size_t)HID * HID * 2);
    u16* W1Th = (u16*)alloc((size_t)HID * HID * 2);
    u16* W2Th = (u16*)alloc((size_t)HID * HID * 2);
    u16* F0Th = (u16*)alloc((size_t)HID * FCU * 2);
    __half* W1f = (__half*)alloc((size_t)FCU * NCLS * 2);
    __half* bufG = (__half*)alloc((size_t)NNODES * HID * 2);
    u16* R1 = (u16*)alloc((size_t)2 * NNODES * DIM * 2);
    u16* xh = R1, *xl = R1 + (size_t)NNODES * DIM;
    u16* h1H = R1,                            *h1L = R1 + (size_t)NNODES * HID;
    u16* B3H = R1 + (size_t)2 * NNODES * HID;

    const int M = NNODES;
    hipMemsetAsync(degS, 0, (size_t)NNODES * 4, stream);

    histDeg<<<4 * DSLICE, 256, 0, stream>>>(ei, degS);
    norm_kernel<<<(NNODES + 255) / 256, 256, 0, stream>>>(degS, nrm);
    histA<<<NBLK_A, 1024, 0, stream>>>(ei, hist);
    scanh_a<<<16, 1024, 0, stream>>>(hist, bsum);
    scanh_b<<<1, 64, 0, stream>>>(bsum);
    scanh_c<<<16, 1024, 0, stream>>>(hist, bsum);
    bucket_fill<<<NBLK_A, 1024, 0, stream>>>(ei, hist, packed);
    bucket_csr<<<NBKT, 256, 0, stream>>>(packed, hist, rowptr, csr);

    conv_x<<<(NNODES * DIM / 4 + 255) / 256, 256, 0, stream>>>(x, xh, xl);
    conv_wT<<<(DIM * HID + 255) / 256, 256, 0, stream>>>(gcn0W, DIM, HID, W0Th, W0Tl);
    conv_weights<<<768, 256, 0, stream>>>(fc0W, F0Th, w1, w1Th, gcn1W, W1Th, gcn2W, W2Th, fc1W, W1f);

    const int GB = (M + 63) / 64;
    const int GB32 = (M + 31) / 32;
    const int AB = (NNODES + 3) / 4;
    // gcn0 (full split: raw-input scale)
    gemm_split<DIM, 0, 3><<<GB, 256, 0, stream>>>(xh, xl, W0Th, W0Tl, nullptr, nrm, bufG, nullptr, M);
    agg_fast<0, 1><<<AB, 256, 0, stream>>>(bufG, nrm, rowptr, csr, gcn0b, h1H, h1L);
    // h11 = relu(h1@w1 + b1): single-plane
    gemm_split<HID, 2, 1><<<GB, 256, 0, stream>>>(h1H, nullptr, w1Th, nullptr, b1, nullptr, nullptr, B3H, M);
    // gcn1 (no relu): single-plane
    gemm_split<HID, 0, 1><<<GB, 256, 0, stream>>>(B3H, nullptr, W1Th, nullptr, nullptr, nrm, bufG, nullptr, M);
    agg_fast<1, 0><<<AB, 256, 0, stream>>>(bufG, nrm, rowptr, csr, gcn1b, B3H, nullptr);
    // gcn2: single-plane GEMM -> fused agg2 + fc head
    gemm_split<HID, 0, 1><<<GB, 256, 0, stream>>>(B3H, nullptr, W2Th, nullptr, nullptr, nrm, bufG, nullptr, M);
    agg_fc<<<GB32, 256, 0, stream>>>(bufG, nrm, rowptr, csr, gcn2b, h1H, h1L,
                                     F0Th, fc0b, W1f, fc1b, out, M);
}

// Round 15
// 412.441 us; speedup vs baseline: 1.1413x; 1.1413x over previous
//
#include <hip/hip_runtime.h>
#include <hip/hip_bf16.h>
#include <hip/hip_fp16.h>
#include <cstddef>
#include <cstdint>

#define NNODES 50000
#define NEDGES 1600000
#define DIM 256
#define HID 128
#define FCU 1024
#define NCLS 16

// CSR-build geometry
#define NBKT 256
#define BW 196
#define NBLK_A 64
#define EPB (NEDGES / NBLK_A)
#define CAPB 8192

// degree-histogram geometry
#define DCHUNK 12800
#define DSLICE 64
#define DEPB (NEDGES / DSLICE)

typedef short s16x8 __attribute__((ext_vector_type(8)));
typedef _Float16 f16x8 __attribute__((ext_vector_type(8)));
typedef float f32x4 __attribute__((ext_vector_type(4)));
#define MFMA16 __builtin_amdgcn_mfma_f32_16x16x32_bf16
#define MFMAH  __builtin_amdgcn_mfma_f32_16x16x32_f16

typedef unsigned short u16;
typedef unsigned int u32;

__device__ inline u16 f2bf(float f) {
    u32 u = __float_as_uint(f);
    return (u16)((u + 0x7FFF + ((u >> 16) & 1)) >> 16);
}
__device__ inline float bf2f(u16 h) { return __uint_as_float(((u32)h) << 16); }
__device__ inline void split2(float v, u16& h, u16& l) {
    h = f2bf(v);
    l = f2bf(v - bf2f(h));
}

// ---------------- graph preprocessing ----------------

__global__ __launch_bounds__(256) void histDeg(const int* __restrict__ ei, int* __restrict__ degS) {
    __shared__ int h[DCHUNK];
    int chunk = blockIdx.x >> 6;
    int slice = blockIdx.x & (DSLICE - 1);
    int t = threadIdx.x;
    int base0 = chunk * DCHUNK;
    for (int i = t; i < DCHUNK; i += 256) h[i] = 0;
    __syncthreads();
    int base = slice * DEPB;
    for (int e = base + t; e < base + DEPB; e += 256) {
        int s = ei[e] - base0;
        if ((unsigned)s < (unsigned)DCHUNK) atomicAdd(&h[s], 1);
    }
    __syncthreads();
    int lim = NNODES - base0; if (lim > DCHUNK) lim = DCHUNK;
    for (int i = t; i < lim; i += 256) {
        int v = h[i];
        if (v) atomicAdd(&degS[base0 + i], v);
    }
}

__global__ void norm_kernel(const int* __restrict__ degS, float* __restrict__ nrm) {
    int i = blockIdx.x * blockDim.x + threadIdx.x;
    if (i < NNODES) nrm[i] = rsqrtf((float)(degS[i] + 1));
}

__global__ __launch_bounds__(1024) void histA(const int* __restrict__ ei, int* __restrict__ hist) {
    __shared__ int h[NBKT];
    int blk = blockIdx.x, t = threadIdx.x;
    if (t < NBKT) h[t] = 0;
    __syncthreads();
    int base = blk * EPB;
    for (int e = base + t; e < base + EPB; e += 1024) {
        int dst = ei[NEDGES + e];
        atomicAdd(&h[dst / BW], 1);
    }
    __syncthreads();
    if (t < NBKT) hist[t * NBLK_A + blk] = h[t];
}

__global__ __launch_bounds__(1024) void scanh_a(int* __restrict__ hist, int* __restrict__ bsum) {
    __shared__ int s[1024];
    int b = blockIdx.x, t = threadIdx.x, i = b * 1024 + t;
    int v = hist[i];
    s[t] = v;
    __syncthreads();
    for (int off = 1; off < 1024; off <<= 1) {
        int x = (t >= off) ? s[t - off] : 0;
        __syncthreads();
        s[t] += x;
        __syncthreads();
    }
    hist[i] = s[t] - v;
    if (t == 1023) bsum[b] = s[1023];
}
__global__ void scanh_b(int* __restrict__ bsum) {
    if (threadIdx.x == 0 && blockIdx.x == 0) {
        int a = 0;
        for (int j = 0; j < 16; ++j) { int t = bsum[j]; bsum[j] = a; a += t; }
    }
}
__global__ __launch_bounds__(1024) void scanh_c(int* __restrict__ hist, const int* __restrict__ bsum) {
    int i = blockIdx.x * 1024 + threadIdx.x;
    hist[i] += bsum[blockIdx.x];
}

__global__ __launch_bounds__(1024) void bucket_fill(const int* __restrict__ ei,
                                                    const int* __restrict__ hist,
                                                    u32* __restrict__ packed) {
    __shared__ int cur[NBKT];
    int blk = blockIdx.x, t = threadIdx.x;
    if (t < NBKT) cur[t] = hist[t * NBLK_A + blk];
    __syncthreads();
    int base = blk * EPB;
    for (int e = base + t; e < base + EPB; e += 1024) {
        int src = ei[e], dst = ei[NEDGES + e];
        int p = atomicAdd(&cur[dst / BW], 1);
        packed[p] = ((u32)dst << 16) | (u32)src;
    }
}

__global__ __launch_bounds__(256) void bucket_csr(const u32* __restrict__ packed,
                                                  const int* __restrict__ hist,
                                                  int* __restrict__ rowptr, u16* __restrict__ csr) {
    __shared__ u32 st[CAPB];
    __shared__ u16 so[CAPB];
    __shared__ int cnt[256], excl[256];
    int b = blockIdx.x, t = threadIdx.x;
    int ebase = hist[b * NBLK_A];
    int eend  = (b < NBKT - 1) ? hist[(b + 1) * NBLK_A] : NEDGES;
    int nE = eend - ebase;
    if (nE > CAPB) nE = CAPB;
    cnt[t] = 0;
    __syncthreads();
    for (int i = t; i < nE; i += 256) {
        u32 p = packed[ebase + i];
        st[i] = p;
        atomicAdd(&cnt[(int)(p >> 16) - b * BW], 1);
    }
    __syncthreads();
    int v = cnt[t];
    excl[t] = v;
    __syncthreads();
    for (int off = 1; off < 256; off <<= 1) {
        int x = (t >= off) ? excl[t - off] : 0;
        __syncthreads();
        excl[t] += x;
        __syncthreads();
    }
    int ex = excl[t] - v;
    int node = b * BW + t;
    if (t < BW && node < NNODES) rowptr[node] = ebase + ex;
    if (b == NBKT - 1 && t == 0) rowptr[NNODES] = NEDGES;
    cnt[t] = ex;
    __syncthreads();
    for (int i = t; i < nE; i += 256) {
        u32 p = st[i];
        int pos = atomicAdd(&cnt[(int)(p >> 16) - b * BW], 1);
        so[pos] = (u16)(p & 0xFFFF);
    }
    __syncthreads();
    for (int i = t; i < nE; i += 256) csr[ebase + i] = so[i];
}

// ---------------- conversions ----------------

__global__ __launch_bounds__(256) void conv_x(const float* __restrict__ x,
                                              u16* __restrict__ xh, u16* __restrict__ xl) {
    int i = blockIdx.x * blockDim.x + threadIdx.x;
    const float4 v = *reinterpret_cast<const float4*>(x + (size_t)i * 4);
    u16 h0, l0, h1, l1, h2, l2, h3, l3;
    split2(v.x, h0, l0); split2(v.y, h1, l1); split2(v.z, h2, l2); split2(v.w, h3, l3);
    ushort4 hv = make_ushort4(h0, h1, h2, h3), lv = make_ushort4(l0, l1, l2, l3);
    *reinterpret_cast<ushort4*>(xh + (size_t)i * 4) = hv;
    *reinterpret_cast<ushort4*>(xl + (size_t)i * 4) = lv;
}

// gcn0W only: hi/lo transposed planes (split-3 consumer)
__global__ __launch_bounds__(256) void conv_wT(const float* __restrict__ W, int K, int N,
                                               u16* __restrict__ outH, u16* __restrict__ outL) {
    int o = blockIdx.x * blockDim.x + threadIdx.x;
    if (o < K * N) {
        int n = o / K, k = o - n * K;
        u16 h, l;
        split2(W[(size_t)k * N + n], h, l);
        outH[o] = h; outL[o] = l;
    }
}

// all single-plane weight conversions fused
__global__ __launch_bounds__(256) void conv_weights(
    const float* __restrict__ fc0W, u16* __restrict__ F0Th,
    const float* __restrict__ w1,    u16* __restrict__ w1Th,
    const float* __restrict__ gcn1W, u16* __restrict__ W1Th,
    const float* __restrict__ gcn2W, u16* __restrict__ W2Th,
    const float* __restrict__ fc1W,  __half* __restrict__ W1f)
{
    int b = blockIdx.x, t = threadIdx.x;
    if (b < 512) {
        int o = b * 256 + t;
        int n = o >> 7, k = o & 127;
        F0Th[o] = f2bf(fc0W[(size_t)k * FCU + n]);
    } else if (b < 576) {
        int o = (b - 512) * 256 + t;
        int n = o >> 7, k = o & 127;
        w1Th[o] = f2bf(w1[(size_t)k * HID + n]);
    } else if (b < 640) {
        int o = (b - 576) * 256 + t;
        int n = o >> 7, k = o & 127;
        W1Th[o] = f2bf(gcn1W[(size_t)k * HID + n]);
    } else if (b < 704) {
        int o = (b - 640) * 256 + t;
        int n = o >> 7, k = o & 127;
        W2Th[o] = f2bf(gcn2W[(size_t)k * HID + n]);
    } else {
        int o = (b - 704) * 256 + t;
        int n = o >> 10, k = o & 1023;
        W1f[o] = __float2half(fc1W[(size_t)k * NCLS + n]);
    }
}

// ---------------- aggregation (round-9 proven) ----------------
// VAR 0: relu  VAR 1: plain  VAR 2: relu + h1 residual
// WLO: also write lo plane

template<int VAR, int WLO>
__global__ __launch_bounds__(256) void agg_fast(
    const __half* __restrict__ g, const float* __restrict__ nrm,
    const int* __restrict__ rowptr, const u16* __restrict__ csr,
    const float* __restrict__ bias,
    const u16* __restrict__ h1H, const u16* __restrict__ h1L,
    u16* __restrict__ outH, u16* __restrict__ outL)
{
    int w = threadIdx.x >> 6, lane = threadIdx.x & 63;
    int i = blockIdx.x * 4 + w;
    if (i >= NNODES) return;
    const __half2* gp = reinterpret_cast<const __half2*>(g);
    size_t lrow = (size_t)i * 64 + lane;
    float2 acc = __half22float2(gp[lrow]);
    int e0 = rowptr[i], e1 = rowptr[i + 1];
    int e = e0;
    for (; e + 8 <= e1; e += 8) {
        int s[8];
#pragma unroll
        for (int q = 0; q < 8; ++q) s[q] = csr[e + q];
        __half2 v[8];
#pragma unroll
        for (int q = 0; q < 8; ++q) v[q] = gp[(size_t)s[q] * 64 + lane];
#pragma unroll
        for (int q = 0; q < 8; ++q) {
            float2 f = __half22float2(v[q]);
            acc.x += f.x; acc.y += f.y;
        }
    }
    for (; e < e1; ++e) {
        int s = csr[e];
        float2 f = __half22float2(gp[(size_t)s * 64 + lane]);
        acc.x += f.x; acc.y += f.y;
    }
    float ni = nrm[i];
    const float2 b = *reinterpret_cast<const float2*>(bias + lane * 2);
    float v0 = fmaf(ni, acc.x, b.x);
    float v1 = fmaf(ni, acc.y, b.y);
    if (VAR != 1) { v0 = fmaxf(v0, 0.f); v1 = fmaxf(v1, 0.f); }
    if (VAR == 2) {
        ushort2 rh = *reinterpret_cast<const ushort2*>(h1H + (size_t)i * HID + lane * 2);
        ushort2 rl = *reinterpret_cast<const ushort2*>(h1L + (size_t)i * HID + lane * 2);
        v0 += bf2f(rh.x) + bf2f(rl.x);
        v1 += bf2f(rh.y) + bf2f(rl.y);
    }
    if (WLO) {
        u16 h0, l0, h1v, l1v;
        split2(v0, h0, l0);
        split2(v1, h1v, l1v);
        *reinterpret_cast<ushort2*>(outH + (size_t)i * HID + lane * 2) = make_ushort2(h0, h1v);
        *reinterpret_cast<ushort2*>(outL + (size_t)i * HID + lane * 2) = make_ushort2(l0, l1v);
    } else {
        *reinterpret_cast<ushort2*>(outH + (size_t)i * HID + lane * 2) = make_ushort2(f2bf(v0), f2bf(v1));
    }
}

// ---------------- split/single-plane bf16 MFMA GEMM: [M,K] @ [K,128] ----------------
// PL=3: hi/lo split (3 MFMA).  PL=1: hi-plane only.
// MODE 0: out fp16 scaled by nrm[r].  MODE 2: per-node bias + relu, bf16-hi out.

template<int K, int MODE, int PL>
__global__ __launch_bounds__(256) void gemm_split(
    const u16* __restrict__ Ah, const u16* __restrict__ Al,
    const u16* __restrict__ BTh, const u16* __restrict__ BTl,
    const float* __restrict__ pnb, const float* __restrict__ nrmv,
    __half* __restrict__ outG, u16* __restrict__ outH, int M)
{
    const int PK = 40;
    __shared__ __align__(16) u16 AsH[64 * PK];
    __shared__ __align__(16) u16 BsH[128 * PK];
    __shared__ __align__(16) u16 AsL[PL == 3 ? 64 * PK : 1];
    __shared__ __align__(16) u16 BsL[PL == 3 ? 128 * PK : 1];
    int tid = threadIdx.x, lane = tid & 63, w = tid >> 6;
    int wr = w >> 1, wc = w & 1;
    int l15 = lane & 15, l4 = lane >> 4;
    int blockRow = blockIdx.x * 64;
    f32x4 acc[2][4] = {};

    for (int kk = 0; kk < K; kk += 32) {
        {
            int row = tid >> 2, kc = (tid & 3) * 8;
            int gr = blockRow + row; if (gr >= M) gr = M - 1;
            *(s16x8*)&AsH[row * PK + kc] = *(const s16x8*)&Ah[(size_t)gr * K + kk + kc];
            if (PL == 3)
                *(s16x8*)&AsL[row * PK + kc] = *(const s16x8*)&Al[(size_t)gr * K + kk + kc];
        }
#pragma unroll
        for (int i2 = 0; i2 < 2; ++i2) {
            int idx = tid + i2 * 256;
            int n = idx >> 2, kc = (idx & 3) * 8;
            *(s16x8*)&BsH[n * PK + kc] = *(const s16x8*)&BTh[(size_t)n * K + kk + kc];
            if (PL == 3)
                *(s16x8*)&BsL[n * PK + kc] = *(const s16x8*)&BTl[(size_t)n * K + kk + kc];
        }
        __syncthreads();
        s16x8 ah[2], al[2], bh[4], bl[4];
#pragma unroll
        for (int mi = 0; mi < 2; ++mi) {
            ah[mi] = *(const s16x8*)&AsH[(wr * 32 + mi * 16 + l15) * PK + 8 * l4];
            if (PL == 3) al[mi] = *(const s16x8*)&AsL[(wr * 32 + mi * 16 + l15) * PK + 8 * l4];
        }
#pragma unroll
        for (int ni = 0; ni < 4; ++ni) {
            bh[ni] = *(const s16x8*)&BsH[(wc * 64 + ni * 16 + l15) * PK + 8 * l4];
            if (PL == 3) bl[ni] = *(const s16x8*)&BsL[(wc * 64 + ni * 16 + l15) * PK + 8 * l4];
        }
#pragma unroll
        for (int mi = 0; mi < 2; ++mi)
#pragma unroll
            for (int ni = 0; ni < 4; ++ni) {
                acc[mi][ni] = MFMA16(ah[mi], bh[ni], acc[mi][ni], 0, 0, 0);
                if (PL == 3) {
                    acc[mi][ni] = MFMA16(ah[mi], bl[ni], acc[mi][ni], 0, 0, 0);
                    acc[mi][ni] = MFMA16(al[mi], bh[ni], acc[mi][ni], 0, 0, 0);
                }
            }
        __syncthreads();
    }
#pragma unroll
    for (int mi = 0; mi < 2; ++mi)
#pragma unroll
        for (int ni = 0; ni < 4; ++ni) {
            int c = wc * 64 + ni * 16 + l15;
#pragma unroll
            for (int j = 0; j < 4; ++j) {
                int r = blockRow + wr * 32 + mi * 16 + l4 * 4 + j;
                if (r < M) {
                    if (MODE == 0) {
                        outG[(size_t)r * 128 + c] = __float2half(nrmv[r] * acc[mi][ni][j]);
                    } else {
                        float v = fmaxf(acc[mi][ni][j] + pnb[(size_t)r * 128 + c], 0.f);
                        outH[(size_t)r * 128 + c] = f2bf(v);
                    }
                }
            }
        }
}

// ---------------- fused fc head (round-11 proven: BM=32, B-prefetch) ----------------

__global__ __launch_bounds__(256) void fc_kernel(
    const u16* __restrict__ Ahi,
    const u16* __restrict__ BTh,
    const float* __restrict__ fc0b,
    const __half* __restrict__ W1f,    // [16][1024] fp16
    const float* __restrict__ fc1b,
    float* __restrict__ out, int M)
{
    __shared__ __align__(16) u16 vs[32 * 128];     // fp16 bits, XOR-swizzled
    __shared__ __align__(16) u16 W1s[16 * 128];    // fp16 bits, XOR-swizzled
    int tid = threadIdx.x, lane = tid & 63, w = tid >> 6;   // w = column quarter
    int l15 = lane & 15, l4 = lane >> 4;
    int blockRow = blockIdx.x * 32;

    s16x8 ahr[2][4];
#pragma unroll
    for (int mi = 0; mi < 2; ++mi) {
        int r = blockRow + mi * 16 + l15; if (r >= M) r = M - 1;
#pragma unroll
        for (int ks = 0; ks < 4; ++ks)
            ahr[mi][ks] = *(const s16x8*)&Ahi[(size_t)r * HID + ks * 32 + 8 * l4];
    }

    f32x4 acc2 = {0.f, 0.f, 0.f, 0.f};
    s16x8 bcur[2][4];
#pragma unroll
    for (int ni = 0; ni < 2; ++ni)
#pragma unroll
        for (int ks = 0; ks < 4; ++ks)
            bcur[ni][ks] = *(const s16x8*)&BTh[(size_t)(w * 32 + ni * 16 + l15) * HID + ks * 32 + 8 * l4];

#pragma unroll
    for (int cc = 0; cc < FCU / 128; ++cc) {
        int co = cc * 128;
        s16x8 bnxt[2][4];
        if (cc + 1 < FCU / 128) {
#pragma unroll
            for (int ni = 0; ni < 2; ++ni)
#pragma unroll
                for (int ks = 0; ks < 4; ++ks)
                    bnxt[ni][ks] = *(const s16x8*)&BTh[(size_t)(co + 128 + w * 32 + ni * 16 + l15) * HID + ks * 32 + 8 * l4];
        }

        f32x4 acc[2][2] = {};
#pragma unroll
        for (int ks = 0; ks < 4; ++ks)
#pragma unroll
            for (int mi = 0; mi < 2; ++mi)
#pragma unroll
                for (int ni = 0; ni < 2; ++ni)
                    acc[mi][ni] = MFMA16(ahr[mi][ks], bcur[ni][ks], acc[mi][ni], 0, 0, 0);

        {
            int cls = tid >> 4, kc = (tid & 15) * 8;
            s16x8 t = *(const s16x8*)&W1f[(size_t)cls * FCU + co + kc];
            *(s16x8*)&W1s[cls * 128 + (kc ^ ((cls & 7) << 3))] = t;
        }
#pragma unroll
        for (int mi = 0; mi < 2; ++mi)
#pragma unroll
            for (int ni = 0; ni < 2; ++ni) {
                int unit = w * 32 + ni * 16 + l15;
                float b0v = fc0b[co + unit];
#pragma unroll
                for (int j = 0; j < 4; ++j) {
                    int rl = mi * 16 + l4 * 4 + j;
                    float v = fmaxf(acc[mi][ni][j] + b0v, 0.f);
                    vs[rl * 128 + (unit ^ ((rl & 7) << 3))] = __half_as_ushort(__float2half(v));
                }
            }
        __syncthreads();

        if (w < 2) {
#pragma unroll
            for (int ks = 0; ks < 4; ++ks) {
                int row = w * 16 + l15;
                int colk = ks * 32 + 8 * l4;
                f16x8 a2 = *(const f16x8*)&vs[row * 128 + (colk ^ ((row & 7) << 3))];
                f16x8 b2 = *(const f16x8*)&W1s[l15 * 128 + (colk ^ ((l15 & 7) << 3))];
                acc2 = MFMAH(a2, b2, acc2, 0, 0, 0);
            }
        }
        __syncthreads();

        if (cc + 1 < FCU / 128) {
#pragma unroll
            for (int ni = 0; ni < 2; ++ni)
#pragma unroll
                for (int ks = 0; ks < 4; ++ks)
                    bcur[ni][ks] = bnxt[ni][ks];
        }
    }

    if (w < 2) {
#pragma unroll
        for (int j = 0; j < 4; ++j) {
            int gr = blockRow + w * 16 + l4 * 4 + j;
            if (gr < M) out[(size_t)gr * NCLS + l15] = acc2[j] + fc1b[l15];
        }
    }
}

// ---------------- launch ----------------

extern "C" void kernel_launch(void* const* d_in, const int* in_sizes, int n_in,
                              void* d_out, int out_size, void* d_ws, size_t ws_size,
                              hipStream_t stream)
{
    const float* x     = (const float*)d_in[0];
    const int*   ei    = (const int*)d_in[1];
    const float* gcn0W = (const float*)d_in[2];
    const float* gcn0b = (const float*)d_in[3];
    const float* gcn1W = (const float*)d_in[4];
    const float* gcn1b = (const float*)d_in[5];
    const float* gcn2W = (const float*)d_in[6];
    const float* gcn2b = (const float*)d_in[7];
    const float* w1    = (const float*)d_in[8];
    const float* b1    = (const float*)d_in[9];
    const float* fc0W  = (const float*)d_in[10];
    const float* fc0b  = (const float*)d_in[11];
    const float* fc1W  = (const float*)d_in[12];
    const float* fc1b  = (const float*)d_in[13];
    float* out = (float*)d_out;

    char* ws = (char*)d_ws;
    size_t off = 0;
    auto alloc = [&](size_t bytes) -> void* {
        void* p = ws + off;
        off = (off + bytes + 255) & ~(size_t)255;
        return p;
    };
    int* degS   = (int*)alloc((size_t)NNODES * 4);
    int* rowptr = (int*)alloc((size_t)(NNODES + 1) * 4);
    int* hist   = (int*)alloc((size_t)NBKT * NBLK_A * 4);
    int* bsum   = (int*)alloc(64 * 4);
    u32* packed = (u32*)alloc((size_t)NEDGES * 4);
    u16* csr    = (u16*)alloc((size_t)NEDGES * 2);
    float* nrm  = (float*)alloc((size_t)NNODES * 4);
    u16* W0Th = (u16*)alloc((size_t)DIM * HID * 2);  u16* W0Tl = (u16*)alloc((size_t)DIM * HID * 2);
    u16* w1Th = (u16*)alloc((size_t)HID * HID * 2);
    u16* W1Th = (u16*)alloc((size_t)HID * HID * 2);
    u16* W2Th = (u16*)alloc((size_t)HID * HID * 2);
    u16* F0Th = (u16*)alloc((size_t)HID * FCU * 2);
    __half* W1f = (__half*)alloc((size_t)FCU * NCLS * 2);
    __half* bufG = (__half*)alloc((size_t)NNODES * HID * 2);
    u16* R1 = (u16*)alloc((size_t)2 * NNODES * DIM * 2);
    u16* xh = R1, *xl = R1 + (size_t)NNODES * DIM;
    u16* h1H = R1,                            *h1L = R1 + (size_t)NNODES * HID;
    u16* B3H = R1 + (size_t)2 * NNODES * HID;

    const int M = NNODES;
    hipMemsetAsync(degS, 0, (size_t)NNODES * 4, stream);

    histDeg<<<4 * DSLICE, 256, 0, stream>>>(ei, degS);
    norm_kernel<<<(NNODES + 255) / 256, 256, 0, stream>>>(degS, nrm);
    histA<<<NBLK_A, 1024, 0, stream>>>(ei, hist);
    scanh_a<<<16, 1024, 0, stream>>>(hist, bsum);
    scanh_b<<<1, 64, 0, stream>>>(bsum);
    scanh_c<<<16, 1024, 0, stream>>>(hist, bsum);
    bucket_fill<<<NBLK_A, 1024, 0, stream>>>(ei, hist, packed);
    bucket_csr<<<NBKT, 256, 0, stream>>>(packed, hist, rowptr, csr);

    conv_x<<<(NNODES * DIM / 4 + 255) / 256, 256, 0, stream>>>(x, xh, xl);
    conv_wT<<<(DIM * HID + 255) / 256, 256, 0, stream>>>(gcn0W, DIM, HID, W0Th, W0Tl);
    conv_weights<<<768, 256, 0, stream>>>(fc0W, F0Th, w1, w1Th, gcn1W, W1Th, gcn2W, W2Th, fc1W, W1f);

    const int GB = (M + 63) / 64;
    const int GB32 = (M + 31) / 32;
    const int AB = (NNODES + 3) / 4;
    // gcn0 (full split: raw-input scale)
    gemm_split<DIM, 0, 3><<<GB, 256, 0, stream>>>(xh, xl, W0Th, W0Tl, nullptr, nrm, bufG, nullptr, M);
    agg_fast<0, 1><<<AB, 256, 0, stream>>>(bufG, nrm, rowptr, csr, gcn0b, nullptr, nullptr, h1H, h1L);
    // h11 = relu(h1@w1 + b1): single-plane
    gemm_split<HID, 2, 1><<<GB, 256, 0, stream>>>(h1H, nullptr, w1Th, nullptr, b1, nullptr, nullptr, B3H, M);
    // gcn1 (no relu): single-plane
    gemm_split<HID, 0, 1><<<GB, 256, 0, stream>>>(B3H, nullptr, W1Th, nullptr, nullptr, nrm, bufG, nullptr, M);
    agg_fast<1, 0><<<AB, 256, 0, stream>>>(bufG, nrm, rowptr, csr, gcn1b, nullptr, nullptr, B3H, nullptr);
    // gcn2 (relu) + residual: single-plane
    gemm_split<HID, 0, 1><<<GB, 256, 0, stream>>>(B3H, nullptr, W2Th, nullptr, nullptr, nrm, bufG, nullptr, M);
    agg_fast<2, 0><<<AB, 256, 0, stream>>>(bufG, nrm, rowptr, csr, gcn2b, h1H, h1L, B3H, nullptr);
    // head
    fc_kernel<<<GB32, 256, 0, stream>>>(B3H, F0Th, fc0b, W1f, fc1b, out, M);
}